// Round 4
// baseline (274.380 us; speedup 1.0000x reference)
//
#include <hip/hip_runtime.h>
#include <cstddef>

#define NB 256     // graphs
#define M 512      // nodes per graph
#define KNN 6      // neighbors
#define C 32       // channels
#define NTOT (NB*M)

__device__ __forceinline__ float dist2(const float4 pm, const float4 pn)
{
    // bit-identical to the 3x-validated formula: sq[m]+sq[n]-2*dot, fma chain
    float dot = fmaf(pm.x, pn.x, fmaf(pm.y, pn.y, pm.z * pn.z));
    return fmaf(-2.f, dot, pm.w + pn.w);
}

// ---------------------------------------------------------------------------
// K1: KNN (values-only med3 scan + threshold re-scan) + folded layer-1 MLP.
// 4 blocks/graph x 512 threads = 4 col-parts x 128 rows. LDS 34.3 KB ->
// 4 blocks/CU. Tie handling exactly matches top_k (lowest index wins).
// ---------------------------------------------------------------------------
__global__ __launch_bounds__(512) void knn_l1_kernel(
    const float* __restrict__ pos, const float* __restrict__ x,
    const float* __restrict__ W1, const float* __restrict__ b1,
    const float* __restrict__ W2, const float* __restrict__ b2,
    int* __restrict__ idx, float* __restrict__ T1)
{
    __shared__ float4 sp[M];             // 8 KB: x,y,z,sq
    __shared__ float  scratch[4224];     // 16.5 KB: pvals[4][128][8] -> m1ex[128][33]
    __shared__ float  tau[128];
    __shared__ int    cnt[128];
    __shared__ int    cidx[128][8];
    __shared__ float  cdst[128][8];

    const int b = blockIdx.x;
    const int g = b >> 2;
    const int rchunk = b & 3;
    const int tid = threadIdx.x;

    const float* p = pos + (size_t)g * M * 3;
    for (int i = tid; i < M; i += 512) {
        float xx = p[3*i], yy = p[3*i+1], zz = p[3*i+2];
        sp[i] = make_float4(xx, yy, zz, fmaf(xx, xx, fmaf(yy, yy, zz * zz)));
    }
    __syncthreads();

    const int part = tid >> 7;        // wave-uniform
    const int rloc = tid & 127;
    const float4 pm = sp[rchunk * 128 + rloc];

    // ---- phase A: per-part top-6 distance VALUES via med3 chain ----
    float d0=INFINITY,d1=INFINITY,d2=INFINITY,d3=INFINITY,d4=INFINITY,d5=INFINITY;
    const int n0 = part * 128;
#pragma unroll 4
    for (int jj = 0; jj < 128; jj++) {
        float dist = dist2(pm, sp[n0 + jj]);
        d5 = __builtin_amdgcn_fmed3f(dist, d4, d5);   // sorted-insert, values only
        d4 = __builtin_amdgcn_fmed3f(dist, d3, d4);
        d3 = __builtin_amdgcn_fmed3f(dist, d2, d3);
        d2 = __builtin_amdgcn_fmed3f(dist, d1, d2);
        d1 = __builtin_amdgcn_fmed3f(dist, d0, d1);
        d0 = fminf(dist, d0);
    }
    {
        float* pv = &scratch[(part * 128 + rloc) * 8];
        pv[0]=d0; pv[1]=d1; pv[2]=d2; pv[3]=d3; pv[4]=d4; pv[5]=d5;
    }
    __syncthreads();

    // ---- phase B: merge 4x6 values -> row threshold tau (6th smallest) ----
    if (tid < 128) {
        const int r = tid;
        float m[6];
#pragma unroll
        for (int k = 0; k < 6; k++) m[k] = scratch[r * 8 + k];
#pragma unroll
        for (int pp = 1; pp < 4; pp++) {
#pragma unroll
            for (int k = 0; k < 6; k++) {
                float v = scratch[(pp * 128 + r) * 8 + k];
                m[5] = __builtin_amdgcn_fmed3f(v, m[4], m[5]);
                m[4] = __builtin_amdgcn_fmed3f(v, m[3], m[4]);
                m[3] = __builtin_amdgcn_fmed3f(v, m[2], m[3]);
                m[2] = __builtin_amdgcn_fmed3f(v, m[1], m[2]);
                m[1] = __builtin_amdgcn_fmed3f(v, m[0], m[1]);
                m[0] = fminf(v, m[0]);
            }
        }
        tau[r] = m[5];
        cnt[r] = 0;
    }
    __syncthreads();

    // ---- phase C: re-scan, collect all cols with dist <= tau (<= 8 kept) ----
    {
        const float t = tau[rloc];
#pragma unroll 4
        for (int jj = 0; jj < 128; jj++) {
            const int n = n0 + jj;
            float dist = dist2(pm, sp[n]);          // bit-identical to phase A
            if (dist <= t) {
                int pos = atomicAdd(&cnt[rloc], 1);
                if (pos < 8) { cidx[rloc][pos] = n; cdst[rloc][pos] = dist; }
            }
        }
    }
    __syncthreads();

    // ---- phase D: finalize 6 per row with exact reference tie rule ----
    if (tid < 128) {
        const int r = tid;
        const float t = tau[r];
        int cmax = cnt[r]; if (cmax > 8) cmax = 8;
        const int node = g * M + rchunk * 128 + r;
        int taken = 0, used = 0;
#pragma unroll
        for (int i = 0; i < 8; i++) {             // all strictly-below-threshold
            if (i < cmax && cdst[r][i] < t && taken < KNN) {
                idx[taken * NTOT + node] = g * M + cidx[r][i];
                taken++; used |= 1 << i;
            }
        }
        for (int pass = 0; pass < KNN && taken < KNN; pass++) {  // ==tau, lowest idx first
            int best = 0x7fffffff, bi = -1;
#pragma unroll
            for (int i = 0; i < 8; i++)
                if (i < cmax && !((used >> i) & 1) && cdst[r][i] == t && cidx[r][i] < best) {
                    best = cidx[r][i]; bi = i;
                }
            if (bi < 0) break;
            used |= 1 << bi;
            idx[taken * NTOT + node] = g * M + best;
            taken++;
        }
        for (; taken < KNN; taken++)              // unreachable safety (bounded idx)
            idx[taken * NTOT + node] = node;
    }
    __syncthreads();   // scratch reused below

    // ---- phase E: folded layer-1: T1[n] = MLP_a([x,pos]) ----
    {
        const int q  = tid >> 7;                  // wave-uniform -> scalar W loads
        const int r2 = tid & 127;
        const int nl = rchunk * 128 + r2;
        const int n  = g * M + nl;
        const float4 pp = sp[nl];
        const float h0 = x[n], h1 = pp.x, h2 = pp.y, h3 = pp.z;
#pragma unroll
        for (int u = 0; u < 8; u++) {
            const int o = q * 8 + u;
            float a = b1[o];
            a = fmaf(W1[o*4+0], h0, a);
            a = fmaf(W1[o*4+1], h1, a);
            a = fmaf(W1[o*4+2], h2, a);
            a = fmaf(W1[o*4+3], h3, a);
            scratch[r2 * 33 + o] = fmaxf(a, 0.f);  // stride 33: conflict-free
        }
        __syncthreads();
        float v[8];
#pragma unroll
        for (int u = 0; u < 8; u++) {
            const int o = q * 8 + u;
            float a = b2[o];
#pragma unroll
            for (int i = 0; i < C; i++)
                a = fmaf(W2[o * C + i], scratch[r2 * 33 + i], a);
            v[u] = a;
        }
        float4* orow = (float4*)(T1 + (size_t)n * C + q * 8);
        orow[0] = make_float4(v[0], v[1], v[2], v[3]);
        orow[1] = make_float4(v[4], v[5], v[6], v[7]);
    }
}

// ---------------------------------------------------------------------------
// K2/K3: Tout[n] = MLP(relu(max_k Tin[nbr(n,k)])). Thread per node,
// NO VGPR-capping launch bound (round-3's (256,4) likely forced spills).
// ---------------------------------------------------------------------------
__global__ __launch_bounds__(256) void layer_kernel(
    const float* __restrict__ Tin, const int* __restrict__ idx,
    const float* __restrict__ W1, const float* __restrict__ b1,
    const float* __restrict__ W2, const float* __restrict__ b2,
    float* __restrict__ Tout)
{
    const int n = blockIdx.x * 256 + threadIdx.x;

    float h[C];
#pragma unroll
    for (int c = 0; c < C; c++) h[c] = -INFINITY;
#pragma unroll
    for (int k = 0; k < KNN; k++) {
        const int j = idx[k * NTOT + n];
        const float4* r = (const float4*)(Tin + (size_t)j * C);
#pragma unroll
        for (int q = 0; q < 8; q++) {
            float4 v = r[q];
            h[4*q+0] = fmaxf(h[4*q+0], v.x);
            h[4*q+1] = fmaxf(h[4*q+1], v.y);
            h[4*q+2] = fmaxf(h[4*q+2], v.z);
            h[4*q+3] = fmaxf(h[4*q+3], v.w);
        }
    }
#pragma unroll
    for (int c = 0; c < C; c++) h[c] = fmaxf(h[c], 0.f);

    float m1[C];
#pragma unroll
    for (int o = 0; o < C; o++) {
        float a = b1[o];
#pragma unroll
        for (int i = 0; i < C; i++) a = fmaf(W1[o * C + i], h[i], a);
        m1[o] = fmaxf(a, 0.f);
    }

    float4* orow = (float4*)(Tout + (size_t)n * C);
#pragma unroll
    for (int o4 = 0; o4 < 8; o4++) {
        float4 v;
        float* vp = &v.x;
#pragma unroll
        for (int u = 0; u < 4; u++) {
            const int o = o4 * 4 + u;
            float a = b2[o];
#pragma unroll
            for (int i = 0; i < C; i++) a = fmaf(W2[o * C + i], m1[i], a);
            vp[u] = a;
        }
        orow[o4] = v;
    }
}

// ---------------------------------------------------------------------------
// K4: h3 = relu(max_k T3src[nbr]); block partial-max over 256 nodes (swizzled
// LDS tree); atomicMax(int) into gmax (valid: relu => h3 >= 0; 0xAA poison is
// negative int, always loses). No T3/H3 ever written to HBM.
// ---------------------------------------------------------------------------
__global__ __launch_bounds__(256) void agg_pool_kernel(
    const float* __restrict__ Tin, const int* __restrict__ idx,
    int* __restrict__ gmax)
{
    __shared__ float S[256 * C];   // 32 KB, elem (r,c) at r*32 + (c ^ (r&31))
    const int t = threadIdx.x;
    const int n = blockIdx.x * 256 + t;
    const int g = blockIdx.x >> 1;

    float h[C];
#pragma unroll
    for (int c = 0; c < C; c++) h[c] = -INFINITY;
#pragma unroll
    for (int k = 0; k < KNN; k++) {
        const int j = idx[k * NTOT + n];
        const float4* r = (const float4*)(Tin + (size_t)j * C);
#pragma unroll
        for (int q = 0; q < 8; q++) {
            float4 v = r[q];
            h[4*q+0] = fmaxf(h[4*q+0], v.x);
            h[4*q+1] = fmaxf(h[4*q+1], v.y);
            h[4*q+2] = fmaxf(h[4*q+2], v.z);
            h[4*q+3] = fmaxf(h[4*q+3], v.w);
        }
    }

    const int sw = t & 31;
#pragma unroll
    for (int c = 0; c < C; c++) S[t * C + (c ^ sw)] = fmaxf(h[c], 0.f);
    __syncthreads();

    for (int s = 128; s >= 32; s >>= 1) {
        if (t < s) {
#pragma unroll
            for (int c = 0; c < C; c++) {
                float a = S[t * C + (c ^ sw)];
                float b2_ = S[(t + s) * C + (c ^ sw)];
                S[t * C + (c ^ sw)] = fmaxf(a, b2_);
            }
        }
        __syncthreads();
    }

    if (t < C) {
        float m = -INFINITY;
#pragma unroll
        for (int r = 0; r < C; r++) m = fmaxf(m, S[r * C + (t ^ r)]);
        atomicMax(&gmax[g * C + t], __float_as_int(m));
    }
}

// ---------------------------------------------------------------------------
// K5: out[g] = Wr @ gmax[g] + br. 1536 threads.
// ---------------------------------------------------------------------------
__global__ __launch_bounds__(256) void head_kernel(
    const int* __restrict__ gmax, const float* __restrict__ Wr,
    const float* __restrict__ br, float* __restrict__ out)
{
    const int gid = blockIdx.x * 256 + threadIdx.x;  // == g*6 + o, < 1536
    const int g = gid / 6, o = gid % 6;
    float a = br[o];
#pragma unroll
    for (int i = 0; i < C; i++)
        a = fmaf(Wr[o * C + i], __int_as_float(gmax[g * C + i]), a);
    out[gid] = a;
}

extern "C" void kernel_launch(void* const* d_in, const int* in_sizes, int n_in,
                              void* d_out, int out_size, void* d_ws, size_t ws_size,
                              hipStream_t stream) {
    const float* x   = (const float*)d_in[0];
    const float* pos = (const float*)d_in[1];
    // d_in[2] = batch (int64) unused: nodes are contiguous M-per-graph
    const float* W1a = (const float*)d_in[3];
    const float* b1a = (const float*)d_in[4];
    const float* W2a = (const float*)d_in[5];
    const float* b2a = (const float*)d_in[6];
    const float* W1b = (const float*)d_in[7];
    const float* b1b = (const float*)d_in[8];
    const float* W2b = (const float*)d_in[9];
    const float* b2b = (const float*)d_in[10];
    const float* W1c = (const float*)d_in[11];
    const float* b1c = (const float*)d_in[12];
    const float* W2c = (const float*)d_in[13];
    const float* b2c = (const float*)d_in[14];
    const float* Wr  = (const float*)d_in[15];
    const float* br  = (const float*)d_in[16];

    char* ws = (char*)d_ws;
    int*   idx  = (int*)ws;                                  // 3 MB [KNN][NTOT]
    int*   gmax = (int*)(ws + (size_t)3402 * 1024);          // 32 KB
    float* Ta   = (float*)(ws + (size_t)4  * 1024 * 1024);   // 16.8 MB
    float* Tb   = (float*)(ws + (size_t)24 * 1024 * 1024);   // 16.8 MB
    float* out  = (float*)d_out;

    knn_l1_kernel<<<NB * 4, 512, 0, stream>>>(pos, x, W1a, b1a, W2a, b2a, idx, Ta);
    layer_kernel <<<NTOT / 256, 256, 0, stream>>>(Ta, idx, W1b, b1b, W2b, b2b, Tb);
    layer_kernel <<<NTOT / 256, 256, 0, stream>>>(Tb, idx, W1c, b1c, W2c, b2c, Ta);
    agg_pool_kernel<<<NTOT / 256, 256, 0, stream>>>(Ta, idx, gmax);
    head_kernel<<<6, 256, 0, stream>>>(gmax, Wr, br, out);
}

// Round 5
// 230.903 us; speedup vs baseline: 1.1883x; 1.1883x over previous
//
#include <hip/hip_runtime.h>
#include <cstddef>

#define NB 256     // graphs
#define M 512      // nodes per graph
#define KNN 6      // neighbors
#define C 32       // channels
#define NTOT (NB*M)

// ---------------------------------------------------------------------------
// KNN: round-3 kernel VERBATIM (67 us, VALUBusy 93%, absmax 0.0 validated).
// 4 blocks/graph, 512 threads = 4 column-parts x 128 rows; idx stored
// transposed [k][NTOT] with GLOBAL node ids.
// ---------------------------------------------------------------------------
__global__ __launch_bounds__(512) void knn_kernel(const float* __restrict__ pos,
                                                  int* __restrict__ idx)
{
    __shared__ float4 sp[M];
    __shared__ float  cd[512][7];
    __shared__ int    ci[512][7];

    const int b      = blockIdx.x;
    const int g      = b >> 2;
    const int rchunk = b & 3;
    const int tid    = threadIdx.x;

    const float* p = pos + (size_t)g * M * 3;
    for (int i = tid; i < M; i += 512) {
        float x = p[3 * i], y = p[3 * i + 1], z = p[3 * i + 2];
        sp[i] = make_float4(x, y, z, fmaf(x, x, fmaf(y, y, z * z)));
    }
    __syncthreads();

    const int part = tid >> 7;
    const int rloc = tid & 127;
    const int row  = rchunk * 128 + rloc;

    const float4 pm = sp[row];
    const float xm = pm.x, ym = pm.y, zm = pm.z, sqm = pm.w;

    float d[KNN]; int id[KNN];
#pragma unroll
    for (int k = 0; k < KNN; k++) { d[k] = INFINITY; id[k] = -1; }

    const int n0 = part * 128;
#pragma unroll 4
    for (int jj = 0; jj < 128; jj++) {
        const int n = n0 + jj;
        const float4 pn = sp[n];
        float dot  = fmaf(xm, pn.x, fmaf(ym, pn.y, zm * pn.z));
        float dist = fmaf(-2.f, dot, sqm + pn.w);
#pragma unroll
        for (int k = KNN - 1; k > 0; k--) {
            bool ck  = dist < d[k];
            bool ck1 = dist < d[k - 1];
            d[k]  = ck1 ? d[k - 1]  : (ck ? dist : d[k]);
            id[k] = ck1 ? id[k - 1] : (ck ? n    : id[k]);
        }
        bool c0 = dist < d[0];
        d[0]  = c0 ? dist : d[0];
        id[0] = c0 ? n    : id[0];
    }

#pragma unroll
    for (int k = 0; k < KNN; k++) { cd[tid][k] = d[k]; ci[tid][k] = id[k]; }
    __syncthreads();

    if (tid < 128) {
        float md[KNN]; int mi[KNN];
#pragma unroll
        for (int k = 0; k < KNN; k++) { md[k] = cd[tid][k]; mi[k] = ci[tid][k]; }
#pragma unroll
        for (int pp = 1; pp < 4; pp++) {
#pragma unroll
            for (int k = 0; k < KNN; k++) {
                float dist = cd[pp * 128 + tid][k];
                int   n    = ci[pp * 128 + tid][k];
#pragma unroll
                for (int q = KNN - 1; q > 0; q--) {
                    bool cq  = dist < md[q];
                    bool cq1 = dist < md[q - 1];
                    md[q] = cq1 ? md[q - 1] : (cq ? dist : md[q]);
                    mi[q] = cq1 ? mi[q - 1] : (cq ? n    : mi[q]);
                }
                bool c0 = dist < md[0];
                md[0] = c0 ? dist : md[0];
                mi[0] = c0 ? n    : mi[0];
            }
        }
        const int node = g * M + rchunk * 128 + tid;
#pragma unroll
        for (int k = 0; k < KNN; k++)
            idx[k * NTOT + node] = g * M + mi[k];
    }
}

// ---------------------------------------------------------------------------
// Layer 1: T0[n] = MLP_a([x, pos]) — no gather. Round-3 version.
// ---------------------------------------------------------------------------
__global__ __launch_bounds__(256) void layer1_kernel(
    const float* __restrict__ x, const float* __restrict__ pos,
    const float* __restrict__ W1, const float* __restrict__ b1,
    const float* __restrict__ W2, const float* __restrict__ b2,
    float* __restrict__ Tout)
{
    const int n = blockIdx.x * 256 + threadIdx.x;
    float h0 = x[n], h1 = pos[3 * n], h2 = pos[3 * n + 1], h3 = pos[3 * n + 2];

    float m1[C];
#pragma unroll
    for (int o = 0; o < C; o++) {
        float a = b1[o];
        a = fmaf(W1[o * 4 + 0], h0, a);
        a = fmaf(W1[o * 4 + 1], h1, a);
        a = fmaf(W1[o * 4 + 2], h2, a);
        a = fmaf(W1[o * 4 + 3], h3, a);
        m1[o] = fmaxf(a, 0.f);
    }

    float4* orow = (float4*)(Tout + (size_t)n * C);
#pragma unroll
    for (int o4 = 0; o4 < 8; o4++) {
        float4 v;
        float* vp = &v.x;
#pragma unroll
        for (int u = 0; u < 4; u++) {
            const int o = o4 * 4 + u;
            float a = b2[o];
#pragma unroll
            for (int i = 0; i < C; i++) a = fmaf(W2[o * C + i], m1[i], a);
            vp[u] = a;
        }
        orow[o4] = v;
    }
}

// ---------------------------------------------------------------------------
// Layers 2,3 v2: COOPERATIVE gather. 256 threads = 32 groups x 8 lanes; a
// group gathers one node's 6 neighbor rows (lane l loads float4 #l of each
// row -> 8 contiguous 128B segments per inst = 16 cache lines, vs 64 for
// thread-per-node). Max in regs, relu, stage h via swizzled LDS, then
// thread-per-node MLP (2048 indep fma chains saturate VALU).
// ---------------------------------------------------------------------------
__global__ __launch_bounds__(256) void layer_kernel(
    const float* __restrict__ Tin, const int* __restrict__ idx,
    const float* __restrict__ W1, const float* __restrict__ b1,
    const float* __restrict__ W2, const float* __restrict__ b2,
    float* __restrict__ Tout)
{
    __shared__ float Hs[256 * C];   // 32 KB; elem (ln,c) at ln*32 + (c ^ (ln&31))
    const int t    = threadIdx.x;
    const int base = blockIdx.x * 256;
    const int grp  = t >> 3;        // 0..31
    const int l    = t & 7;         // 0..7

#pragma unroll
    for (int p = 0; p < 8; p++) {
        const int ln = p * 32 + grp;          // 0..255
        const int n  = base + ln;
        float4 hm = make_float4(-INFINITY, -INFINITY, -INFINITY, -INFINITY);
#pragma unroll
        for (int k = 0; k < KNN; k++) {
            const int j = idx[k * NTOT + n];  // 8 lanes same addr: broadcast
            const float4 v = *(const float4*)(Tin + (size_t)j * C + l * 4);
            hm.x = fmaxf(hm.x, v.x); hm.y = fmaxf(hm.y, v.y);
            hm.z = fmaxf(hm.z, v.z); hm.w = fmaxf(hm.w, v.w);
        }
        const int sw = ln & 31;
        Hs[ln * C + ((4 * l + 0) ^ sw)] = fmaxf(hm.x, 0.f);
        Hs[ln * C + ((4 * l + 1) ^ sw)] = fmaxf(hm.y, 0.f);
        Hs[ln * C + ((4 * l + 2) ^ sw)] = fmaxf(hm.z, 0.f);
        Hs[ln * C + ((4 * l + 3) ^ sw)] = fmaxf(hm.w, 0.f);
    }
    __syncthreads();

    float h[C];
    const int swt = t & 31;
#pragma unroll
    for (int i = 0; i < C; i++) h[i] = Hs[t * C + (i ^ swt)];  // conflict-free

    float m1[C];
#pragma unroll
    for (int o = 0; o < C; o++) {
        float a = b1[o];
#pragma unroll
        for (int i = 0; i < C; i++) a = fmaf(W1[o * C + i], h[i], a);
        m1[o] = fmaxf(a, 0.f);
    }

    float4* orow = (float4*)(Tout + (size_t)(base + t) * C);
#pragma unroll
    for (int o4 = 0; o4 < 8; o4++) {
        float4 v;
        float* vp = &v.x;
#pragma unroll
        for (int u = 0; u < 4; u++) {
            const int o = o4 * 4 + u;
            float a = b2[o];
#pragma unroll
            for (int i = 0; i < C; i++) a = fmaf(W2[o * C + i], m1[i], a);
            vp[u] = a;
        }
        orow[o4] = v;
    }
}

// ---------------------------------------------------------------------------
// K4 v2: cooperative gather from T3, running max across the group's 8 nodes
// in regs, cross-group LDS reduce, relu, 32 atomicMax(int) per block into
// gmax (valid: values >= 0 post-relu; 0xAA poison is negative -> always loses).
// ---------------------------------------------------------------------------
__global__ __launch_bounds__(256) void agg_pool_kernel(
    const float* __restrict__ Tin, const int* __restrict__ idx,
    int* __restrict__ gmax)
{
    __shared__ float R[32 * 33];   // padded: write (g*33 + c)
    const int t    = threadIdx.x;
    const int base = blockIdx.x * 256;
    const int grp  = t >> 3;
    const int l    = t & 7;

    float4 am = make_float4(-INFINITY, -INFINITY, -INFINITY, -INFINITY);
#pragma unroll
    for (int p = 0; p < 8; p++) {
        const int n = base + p * 32 + grp;
#pragma unroll
        for (int k = 0; k < KNN; k++) {
            const int j = idx[k * NTOT + n];
            const float4 v = *(const float4*)(Tin + (size_t)j * C + l * 4);
            am.x = fmaxf(am.x, v.x); am.y = fmaxf(am.y, v.y);
            am.z = fmaxf(am.z, v.z); am.w = fmaxf(am.w, v.w);
        }
    }
    R[grp * 33 + 4 * l + 0] = am.x;
    R[grp * 33 + 4 * l + 1] = am.y;
    R[grp * 33 + 4 * l + 2] = am.z;
    R[grp * 33 + 4 * l + 3] = am.w;
    __syncthreads();

    if (t < C) {
        float m = -INFINITY;
#pragma unroll
        for (int r = 0; r < 32; r++) m = fmaxf(m, R[r * 33 + t]);
        m = fmaxf(m, 0.f);   // relu (monotone: commutes with max)
        const int g = blockIdx.x >> 1;
        atomicMax(&gmax[g * C + t], __float_as_int(m));
    }
}

// ---------------------------------------------------------------------------
// K5: out[g] = Wr @ gmax[g] + br.
// ---------------------------------------------------------------------------
__global__ __launch_bounds__(256) void head_kernel(
    const int* __restrict__ gmax, const float* __restrict__ Wr,
    const float* __restrict__ br, float* __restrict__ out)
{
    const int gid = blockIdx.x * 256 + threadIdx.x;  // < 1536
    const int g = gid / 6, o = gid % 6;
    float a = br[o];
#pragma unroll
    for (int i = 0; i < C; i++)
        a = fmaf(Wr[o * C + i], __int_as_float(gmax[g * C + i]), a);
    out[gid] = a;
}

extern "C" void kernel_launch(void* const* d_in, const int* in_sizes, int n_in,
                              void* d_out, int out_size, void* d_ws, size_t ws_size,
                              hipStream_t stream) {
    const float* x   = (const float*)d_in[0];
    const float* pos = (const float*)d_in[1];
    // d_in[2] = batch (int64) unused: nodes are contiguous M-per-graph
    const float* W1a = (const float*)d_in[3];
    const float* b1a = (const float*)d_in[4];
    const float* W2a = (const float*)d_in[5];
    const float* b2a = (const float*)d_in[6];
    const float* W1b = (const float*)d_in[7];
    const float* b1b = (const float*)d_in[8];
    const float* W2b = (const float*)d_in[9];
    const float* b2b = (const float*)d_in[10];
    const float* W1c = (const float*)d_in[11];
    const float* b1c = (const float*)d_in[12];
    const float* W2c = (const float*)d_in[13];
    const float* b2c = (const float*)d_in[14];
    const float* Wr  = (const float*)d_in[15];
    const float* br  = (const float*)d_in[16];

    char* ws = (char*)d_ws;
    int*   idx  = (int*)ws;                                  // 3 MB [KNN][NTOT]
    int*   gmax = (int*)(ws + (size_t)3584 * 1024);          // 32 KB
    float* Ta   = (float*)(ws + (size_t)4  * 1024 * 1024);   // 16.8 MB
    float* Tb   = (float*)(ws + (size_t)24 * 1024 * 1024);   // 16.8 MB
    float* out  = (float*)d_out;

    knn_kernel<<<NB * 4, 512, 0, stream>>>(pos, idx);
    layer1_kernel<<<NTOT / 256, 256, 0, stream>>>(x, pos, W1a, b1a, W2a, b2a, Ta);
    layer_kernel <<<NTOT / 256, 256, 0, stream>>>(Ta, idx, W1b, b1b, W2b, b2b, Tb);
    layer_kernel <<<NTOT / 256, 256, 0, stream>>>(Tb, idx, W1c, b1c, W2c, b2c, Ta);
    agg_pool_kernel<<<NTOT / 256, 256, 0, stream>>>(Ta, idx, gmax);
    head_kernel<<<6, 256, 0, stream>>>(gmax, Wr, br, out);
}

// Round 6
// 203.285 us; speedup vs baseline: 1.3497x; 1.1359x over previous
//
#include <hip/hip_runtime.h>
#include <cstddef>

#define NB 256     // graphs
#define M 512      // nodes per graph
#define KNN 6      // neighbors
#define C 32       // channels
#define NTOT (NB*M)

// ---------------------------------------------------------------------------
// KNN: round-3/5 kernel VERBATIM (67 us, VALUBusy 93%, absmax 0.0, 3x proven).
// 4 blocks/graph, 512 threads = 4 column-parts x 128 rows; idx stored
// transposed [k][NTOT] with GLOBAL node ids.
// ---------------------------------------------------------------------------
__global__ __launch_bounds__(512) void knn_kernel(const float* __restrict__ pos,
                                                  int* __restrict__ idx)
{
    __shared__ float4 sp[M];
    __shared__ float  cd[512][7];
    __shared__ int    ci[512][7];

    const int b      = blockIdx.x;
    const int g      = b >> 2;
    const int rchunk = b & 3;
    const int tid    = threadIdx.x;

    const float* p = pos + (size_t)g * M * 3;
    for (int i = tid; i < M; i += 512) {
        float x = p[3 * i], y = p[3 * i + 1], z = p[3 * i + 2];
        sp[i] = make_float4(x, y, z, fmaf(x, x, fmaf(y, y, z * z)));
    }
    __syncthreads();

    const int part = tid >> 7;
    const int rloc = tid & 127;
    const int row  = rchunk * 128 + rloc;

    const float4 pm = sp[row];
    const float xm = pm.x, ym = pm.y, zm = pm.z, sqm = pm.w;

    float d[KNN]; int id[KNN];
#pragma unroll
    for (int k = 0; k < KNN; k++) { d[k] = INFINITY; id[k] = -1; }

    const int n0 = part * 128;
#pragma unroll 4
    for (int jj = 0; jj < 128; jj++) {
        const int n = n0 + jj;
        const float4 pn = sp[n];
        float dot  = fmaf(xm, pn.x, fmaf(ym, pn.y, zm * pn.z));
        float dist = fmaf(-2.f, dot, sqm + pn.w);
#pragma unroll
        for (int k = KNN - 1; k > 0; k--) {
            bool ck  = dist < d[k];
            bool ck1 = dist < d[k - 1];
            d[k]  = ck1 ? d[k - 1]  : (ck ? dist : d[k]);
            id[k] = ck1 ? id[k - 1] : (ck ? n    : id[k]);
        }
        bool c0 = dist < d[0];
        d[0]  = c0 ? dist : d[0];
        id[0] = c0 ? n    : id[0];
    }

#pragma unroll
    for (int k = 0; k < KNN; k++) { cd[tid][k] = d[k]; ci[tid][k] = id[k]; }
    __syncthreads();

    if (tid < 128) {
        float md[KNN]; int mi[KNN];
#pragma unroll
        for (int k = 0; k < KNN; k++) { md[k] = cd[tid][k]; mi[k] = ci[tid][k]; }
#pragma unroll
        for (int pp = 1; pp < 4; pp++) {
#pragma unroll
            for (int k = 0; k < KNN; k++) {
                float dist = cd[pp * 128 + tid][k];
                int   n    = ci[pp * 128 + tid][k];
#pragma unroll
                for (int q = KNN - 1; q > 0; q--) {
                    bool cq  = dist < md[q];
                    bool cq1 = dist < md[q - 1];
                    md[q] = cq1 ? md[q - 1] : (cq ? dist : md[q]);
                    mi[q] = cq1 ? mi[q - 1] : (cq ? n    : mi[q]);
                }
                bool c0 = dist < md[0];
                md[0] = c0 ? dist : md[0];
                mi[0] = c0 ? n    : mi[0];
            }
        }
        const int node = g * M + rchunk * 128 + tid;
#pragma unroll
        for (int k = 0; k < KNN; k++)
            idx[k * NTOT + node] = g * M + mi[k];
    }
}

// ---------------------------------------------------------------------------
// Fused layers 1-3 + pool + head. 1 block = 1 graph, thread = node.
// T staged in 64 KB LDS with float4-chunk XOR swizzle:
//   row n, logical chunk q (4 floats) lives at float-idx n*32 + (q^(n&7))*4.
// Writes: lanes n=0..63 writing chunk q hit 8 distinct 16B spans covering all
// 32 banks -> conflict-free. Gather reads (random row j): ~1.5x min phases.
// __launch_bounds__(512,1): 256-VGPR budget -> NO spills (round-2 failure
// mode: default bound capped 128 VGPR -> 108 MB scratch traffic to HBM).
// ---------------------------------------------------------------------------
template <int IN>
__device__ __forceinline__ void gcn_layer_fused(float (&h)[C],
    const float* __restrict__ W1, const float* __restrict__ b1,
    const float* __restrict__ W2, const float* __restrict__ b2,
    float* Ts, int t, const int (&j)[KNN])
{
    float m1[C];
#pragma unroll
    for (int o = 0; o < C; o++) {
        float a = b1[o];
#pragma unroll
        for (int i = 0; i < IN; i++) a = fmaf(W1[o * IN + i], h[i], a);
        m1[o] = fmaxf(a, 0.f);
    }

    const int tp = t & 7;
#pragma unroll
    for (int q = 0; q < 8; q++) {
        float4 v;
        float* vp = &v.x;
#pragma unroll
        for (int u = 0; u < 4; u++) {
            const int o = 4 * q + u;
            float a = b2[o];
#pragma unroll
            for (int i = 0; i < C; i++) a = fmaf(W2[o * C + i], m1[i], a);
            vp[u] = a;
        }
        *(float4*)&Ts[t * C + ((q ^ tp) << 2)] = v;
    }
    __syncthreads();

#pragma unroll
    for (int c = 0; c < C; c++) h[c] = -INFINITY;
#pragma unroll
    for (int k = 0; k < KNN; k++) {
        const int jl = j[k], jp = jl & 7;
#pragma unroll
        for (int q = 0; q < 8; q++) {
            const float4 v = *(const float4*)&Ts[jl * C + ((q ^ jp) << 2)];
            h[4*q+0] = fmaxf(h[4*q+0], v.x);
            h[4*q+1] = fmaxf(h[4*q+1], v.y);
            h[4*q+2] = fmaxf(h[4*q+2], v.z);
            h[4*q+3] = fmaxf(h[4*q+3], v.w);
        }
    }
#pragma unroll
    for (int c = 0; c < C; c++) h[c] = fmaxf(h[c], 0.f);   // relu(gcn(...))
    __syncthreads();   // Ts free for next use
}

__global__ __launch_bounds__(512, 1) void fused_kernel(
    const float* __restrict__ x, const float* __restrict__ pos,
    const int* __restrict__ idx,
    const float* __restrict__ W1a, const float* __restrict__ b1a,
    const float* __restrict__ W2a, const float* __restrict__ b2a,
    const float* __restrict__ W1b, const float* __restrict__ b1b,
    const float* __restrict__ W2b, const float* __restrict__ b2b,
    const float* __restrict__ W1c, const float* __restrict__ b1c,
    const float* __restrict__ W2c, const float* __restrict__ b2c,
    const float* __restrict__ Wr,  const float* __restrict__ br,
    float* __restrict__ out)
{
    __shared__ __align__(16) float Ts[M * C];   // 64 KB
    const int g = blockIdx.x, t = threadIdx.x;
    const int n = g * M + t;

    int j[KNN];
#pragma unroll
    for (int k = 0; k < KNN; k++) j[k] = idx[k * NTOT + n] & (M - 1); // local id

    float h[C];
    h[0] = x[n];
    h[1] = pos[3 * n];
    h[2] = pos[3 * n + 1];
    h[3] = pos[3 * n + 2];

    gcn_layer_fused<4>(h, W1a, b1a, W2a, b2a, Ts, t, j);
    gcn_layer_fused<C>(h, W1b, b1b, W2b, b2b, Ts, t, j);
    gcn_layer_fused<C>(h, W1c, b1c, W2c, b2c, Ts, t, j);
    // h = relu(gcn_c) per node

    // ---- global max pool over 512 nodes (reuse Ts, same chunk swizzle) ----
    const int tp = t & 7;
#pragma unroll
    for (int q = 0; q < 8; q++) {
        float4 v = make_float4(h[4*q], h[4*q+1], h[4*q+2], h[4*q+3]);
        *(float4*)&Ts[t * C + ((q ^ tp) << 2)] = v;
    }
    __syncthreads();

    // tree reduce rows 512 -> 32 (s % 8 == 0 => (t+s)&7 == t&7, same phys)
    for (int s = 256; s >= 32; s >>= 1) {
        if (t < s) {
#pragma unroll
            for (int q = 0; q < 8; q++) {
                const int ph = (q ^ tp) << 2;
                float4 a = *(const float4*)&Ts[t * C + ph];
                float4 b = *(const float4*)&Ts[(t + s) * C + ph];
                a.x = fmaxf(a.x, b.x); a.y = fmaxf(a.y, b.y);
                a.z = fmaxf(a.z, b.z); a.w = fmaxf(a.w, b.w);
                *(float4*)&Ts[t * C + ph] = a;
            }
        }
        __syncthreads();
    }

    if (t < C) {   // wave 0: reduce final 32 rows; channel t across rows r
        float m = -INFINITY;
#pragma unroll
        for (int r = 0; r < 32; r++)
            m = fmaxf(m, Ts[r * C + ((((t >> 2) ^ (r & 7)) << 2) | (t & 3))]);
        Ts[t] = m;   // in-wave: all 32 reads precede the write (program order)
    }
    __syncthreads();

    if (t < 6) {
        float a = br[t];
#pragma unroll
        for (int i = 0; i < C; i++) a = fmaf(Wr[t * C + i], Ts[i], a);
        out[g * 6 + t] = a;
    }
}

extern "C" void kernel_launch(void* const* d_in, const int* in_sizes, int n_in,
                              void* d_out, int out_size, void* d_ws, size_t ws_size,
                              hipStream_t stream) {
    const float* x   = (const float*)d_in[0];
    const float* pos = (const float*)d_in[1];
    // d_in[2] = batch (int64) unused: nodes are contiguous M-per-graph
    const float* W1a = (const float*)d_in[3];
    const float* b1a = (const float*)d_in[4];
    const float* W2a = (const float*)d_in[5];
    const float* b2a = (const float*)d_in[6];
    const float* W1b = (const float*)d_in[7];
    const float* b1b = (const float*)d_in[8];
    const float* W2b = (const float*)d_in[9];
    const float* b2b = (const float*)d_in[10];
    const float* W1c = (const float*)d_in[11];
    const float* b1c = (const float*)d_in[12];
    const float* W2c = (const float*)d_in[13];
    const float* b2c = (const float*)d_in[14];
    const float* Wr  = (const float*)d_in[15];
    const float* br  = (const float*)d_in[16];

    int*   idx = (int*)d_ws;   // 3 MB [KNN][NTOT]
    float* out = (float*)d_out;

    knn_kernel<<<NB * 4, 512, 0, stream>>>(pos, idx);

    fused_kernel<<<NB, 512, 0, stream>>>(x, pos, idx,
                                         W1a, b1a, W2a, b2a,
                                         W1b, b1b, W2b, b2b,
                                         W1c, b1c, W2c, b2c,
                                         Wr, br, out);
}